// Round 7
// baseline (11.135 us; speedup 1.0000x reference)
//
#include <hip/hip_runtime.h>

namespace {
constexpr float INVL  = (float)(1.0 / (1.5 * 0.026) * 1.4426950408889634);   // inv * log2(e)
constexpr float C2L   = (float)(0.1 / (1.5 * 0.026) * 1.4426950408889634);   // VD * inv * log2(e)
constexpr float CLIPL = (float)(30.0 * 1.4426950408889634);                  // 30 * log2(e)
constexpr float SCALE = (float)(0.0005625 * 5.0e6 * 0.6931471805599453 * 0.6931471805599453); // ALPHA*TIA*ln2^2
constexpr float CUT_DELTA = (float)(4.0 * (1.5 * 0.026));   // drop terms <= 0.93 abs each; 288x bound 268 << 2e4 threshold
}

// ONE kernel, 256 blocks (one per CU) x 1024 threads (16 waves), 1 block/CU.
// Block: (b, row h) -> full output row, 64 oc x 32 w. Wave wv = pixels {wv, wv+16},
// lane = oc. theta staged ONCE per CU via float4 into conflict-free LDS layout
// ths[c4*257 + k*64 + oc] (col = 4*c4+k; bank = (c4+oc)%32, 2/bank on write and
// compute read). Global theta min folds into the same pass -> skip cutoff
// (term <= sp(-4)^2*A*T ~ 0.93 dropped; sum bound 268 << 2e4 threshold).
// x halo rows h-1..h+1, full padded width (3x34x32) prescaled; 102 per-position
// channel bitmasks; compute iterates set bits (wave-uniform scalar loop).
// Output transposed through reused ths-LDS -> coalesced float2 row stores.
__global__ __launch_bounds__(1024, 8) void ekv_fused(const float* __restrict__ x,
                                                     const float* __restrict__ theta,
                                                     float* __restrict__ out) {
  __shared__ float    ths[18503];  // theta stage; later reused as os[64][33]
  __shared__ float    xs[32 * 102];  // [c][pos], pos = rr*34 + cl, prescaled
  __shared__ unsigned msk[102];
  __shared__ float    red[16];

  const int blk  = blockIdx.x;
  const int h    = blk & 31;
  const int b    = blk >> 5;
  const int tid  = threadIdx.x;
  const int lane = tid & 63;
  const int wv   = tid >> 6;           // 0..15

  if (tid < 102) msk[tid] = 0u;

  // --- theta stage (float4) + running global min ---
  const float4* t4 = (const float4*)theta;     // 4608 chunks
  float mn = 1e30f;
#pragma unroll
  for (int t = 0; t < 4; ++t) {
    const int j  = t * 1024 + tid;
    const float4 v = t4[j];
    const int oc = j / 72;
    const int c4 = j - oc * 72;
    float* d = &ths[c4 * 257 + oc];
    d[0] = v.x * INVL; d[64] = v.y * INVL; d[128] = v.z * INVL; d[192] = v.w * INVL;
    mn = fminf(mn, fminf(fminf(v.x, v.y), fminf(v.z, v.w)));
  }
  if (tid < 512) {
    const int j  = 4096 + tid;
    const float4 v = t4[j];
    const int oc = j / 72;
    const int c4 = j - oc * 72;
    float* d = &ths[c4 * 257 + oc];
    d[0] = v.x * INVL; d[64] = v.y * INVL; d[128] = v.z * INVL; d[192] = v.w * INVL;
    mn = fminf(mn, fminf(fminf(v.x, v.y), fminf(v.z, v.w)));
  }
#pragma unroll
  for (int off = 32; off; off >>= 1) mn = fminf(mn, __shfl_down(mn, off));
  if (lane == 0) red[wv] = mn;

  // --- stage x halo: rows h-1..h+1, full padded width, zero-padded, prescaled ---
  for (int j = tid; j < 3264; j += 1024) {
    const int c   = j / 102;
    const int pos = j - c * 102;
    const int rr  = pos / 34;
    const int cl  = pos - rr * 34;
    const int gh  = h - 1 + rr;
    const int gw  = cl - 1;
    float v = 0.0f;
    if ((unsigned)gh < 32u && (unsigned)gw < 32u)
      v = x[((b * 32 + c) * 32 + gh) * 32 + gw];
    xs[j] = v * INVL;
  }
  __syncthreads();                               // b1: msk init, ths, xs, red

  // every thread folds the 16 wave-mins (broadcast reads, no extra barrier)
  float cm = red[0];
#pragma unroll
  for (int q = 1; q < 16; ++q) cm = fminf(cm, red[q]);
  const float cutl = (cm - CUT_DELTA) * INVL;

  for (int j = tid; j < 3264; j += 1024) {
    if (xs[j] > cutl) {
      const int c = j / 102;
      atomicOr(&msk[j - c * 102], 1u << c);
    }
  }
  __syncthreads();                               // b2: masks ready

  // --- compute: wave wv -> pixels w = wv, wv+16; lane = oc ---
  float accs[2];
#pragma unroll
  for (int px = 0; px < 2; ++px) {
    const int w = wv + px * 16;
    unsigned mv[9];
#pragma unroll
    for (int p = 0; p < 9; ++p) mv[p] = msk[(p / 3) * 34 + w + (p % 3)];
    float acc = 0.0f;
#pragma unroll
    for (int r = 0; r < 3; ++r) {
#pragma unroll
      for (int dj = 0; dj < 3; ++dj) {
        unsigned m = __builtin_amdgcn_readfirstlane(mv[r * 3 + dj]);
        const int kb = r * 3 + dj;
        const int pb = r * 34 + w + dj;
        while (m) {
          const int c = __builtin_ctz(m);
          m &= m - 1;
          const float vgl = xs[c * 102 + pb];                        // uniform broadcast
          const int col   = c * 9 + kb;
          const float thl = ths[(col >> 2) * 257 + (col & 3) * 64 + lane];  // 2/bank
          const float a1  = vgl - thl;
          const float a1c = fminf(a1, CLIPL);
          const float a2c = fminf(a1 - C2L, CLIPL);
          const float e1  = __builtin_amdgcn_exp2f(a1c);
          const float e2  = __builtin_amdgcn_exp2f(a2c);
          const float l1  = __builtin_amdgcn_logf(1.0f + e1);
          const float l2  = __builtin_amdgcn_logf(1.0f + e2);
          acc = __builtin_fmaf(l1 - l2, l1 + l2, acc);
        }
      }
    }
    accs[px] = acc * SCALE;
  }

  __syncthreads();                               // b3: all ths compute reads done
  ths[lane * 33 + wv]      = accs[0];            // reuse ths as os[64][33]
  ths[lane * 33 + wv + 16] = accs[1];
  __syncthreads();                               // b4: transposed tile ready

  const int oc2 = tid >> 4;                      // 0..63
  const int w2  = (tid & 15) * 2;                // even w
  float2 o;
  o.x = ths[oc2 * 33 + w2];
  o.y = ths[oc2 * 33 + w2 + 1];
  *(float2*)(out + (((b * 64 + oc2) * 32 + h) * 32 + w2)) = o;
}

extern "C" void kernel_launch(void* const* d_in, const int* in_sizes, int n_in,
                              void* d_out, int out_size, void* d_ws, size_t ws_size,
                              hipStream_t stream) {
  const float* x     = (const float*)d_in[0];
  const float* theta = (const float*)d_in[1];
  float* out         = (float*)d_out;
  (void)d_ws; (void)ws_size; (void)in_sizes; (void)n_in; (void)out_size;
  hipLaunchKernelGGL(ekv_fused, dim3(256), dim3(1024), 0, stream, x, theta, out);
}